// Round 3
// baseline (6107.727 us; speedup 1.0000x reference)
//
#include <hip/hip_runtime.h>
#include <math.h>

#define NE 160000
#define NN 10000

#define DEV __device__ __forceinline__
#define LB __launch_bounds__(256, 4)

DEV float fsilu(float x) { return x / (1.0f + __expf(-x)); }
DEV float fsig(float x)  { return 1.0f / (1.0f + __expf(-x)); }

// acc[32] += x[k]*w[k*64+j]; x from global (float4 steps), w uniform (s_load)
template<int K>
DEV void gemm32(const float* __restrict__ src, const float* __restrict__ w,
                float (&acc)[32]) {
#pragma unroll 2
  for (int k = 0; k < K; k += 4) {
    const float4 x4 = *(const float4*)(src + k);
    const float* wr = w + (size_t)k * 64;
#pragma unroll
    for (int j = 0; j < 32; ++j) acc[j] = fmaf(x4.x, wr[j], acc[j]);
#pragma unroll
    for (int j = 0; j < 32; ++j) acc[j] = fmaf(x4.y, wr[64 + j], acc[j]);
#pragma unroll
    for (int j = 0; j < 32; ++j) acc[j] = fmaf(x4.z, wr[128 + j], acc[j]);
#pragma unroll
    for (int j = 0; j < 32; ++j) acc[j] = fmaf(x4.w, wr[192 + j], acc[j]);
  }
}

DEV void store32(float* dst, const float (&a)[32]) {
#pragma unroll
  for (int j = 0; j < 32; j += 4)
    *(float4*)(dst + j) = make_float4(a[j], a[j+1], a[j+2], a[j+3]);
}

// ---------------- chem MLP (272->64->64) + u scalar head ----------------
// 2 threads/edge; LDS stride-65 rows for activation exchange
__global__ void LB
k_chem(const float* __restrict__ h, const float* __restrict__ na,
       const float* __restrict__ ea, const int* __restrict__ edges,
       const float* __restrict__ w1, const float* __restrict__ b1,
       const float* __restrict__ w2, const float* __restrict__ b2,
       const float* __restrict__ wu1, const float* __restrict__ bu1,
       const float* __restrict__ wu2, const float* __restrict__ bu2,
       float* __restrict__ chem, float* __restrict__ ue) {
  __shared__ float lds[128 * 65];
  const int tid = threadIdx.x, eL = tid >> 1, half = tid & 1, co = half * 32;
  const int e = blockIdx.x * 128 + eL;
  const int r = edges[e], c = edges[NE + e];
  float* lrow = lds + eL * 65;

  // layer 1 chunk
  float acc[32];
#pragma unroll
  for (int j = 0; j < 32; ++j) acc[j] = b1[co + j];
  gemm32<64>(h  + (size_t)r * 64, w1 + co,            acc);
  gemm32<64>(h  + (size_t)c * 64, w1 +  64 * 64 + co, acc);
  gemm32<64>(na + (size_t)r * 64, w1 + 128 * 64 + co, acc);
  gemm32<64>(na + (size_t)c * 64, w1 + 192 * 64 + co, acc);
  gemm32<16>(ea + (size_t)e * 16, w1 + 256 * 64 + co, acc);
#pragma unroll
  for (int j = 0; j < 32; ++j) lrow[co + j] = fsilu(acc[j]);
  __syncthreads();

  // layer 2 chunk from LDS
#pragma unroll
  for (int j = 0; j < 32; ++j) acc[j] = b2[co + j];
#pragma unroll 2
  for (int k = 0; k < 64; ++k) {
    const float x = lrow[k];
    const float* wr = w2 + (size_t)k * 64 + co;
#pragma unroll
    for (int j = 0; j < 32; ++j) acc[j] = fmaf(x, wr[j], acc[j]);
  }
#pragma unroll
  for (int j = 0; j < 32; ++j) acc[j] = fsilu(acc[j]);
  store32(chem + (size_t)e * 64 + co, acc);
  __syncthreads();
#pragma unroll
  for (int j = 0; j < 32; ++j) lrow[co + j] = acc[j];   // chem into LDS
  __syncthreads();

  // u head: a3 chunk, partial u
  float a3[32];
#pragma unroll
  for (int j = 0; j < 32; ++j) a3[j] = bu1[co + j];
#pragma unroll 2
  for (int k = 0; k < 64; ++k) {
    const float x = lrow[k];
    const float* wr = wu1 + (size_t)k * 64 + co;
#pragma unroll
    for (int j = 0; j < 32; ++j) a3[j] = fmaf(x, wr[j], a3[j]);
  }
  float up = 0.f;
#pragma unroll
  for (int j = 0; j < 32; ++j) up = fmaf(fsilu(a3[j]), wu2[co + j], up);
  __syncthreads();
  lrow[half] = up;
  __syncthreads();
  if (half == 0) ue[e] = lrow[0] + lrow[1] + bu2[0];
}

// ------------- pos MLP (36->64->64) + x head + x_trans atomics -------------
__global__ void LB
k_pos(const float* __restrict__ coord, const float* __restrict__ nv,
      const float* __restrict__ ea, const int* __restrict__ edges,
      const float* __restrict__ w1, const float* __restrict__ b1,
      const float* __restrict__ w2, const float* __restrict__ b2,
      const float* __restrict__ wx1, const float* __restrict__ bx1,
      const float* __restrict__ wx2, const float* __restrict__ bx2,
      const float* __restrict__ ue,
      float* __restrict__ pos, float* __restrict__ x_sum, float* __restrict__ cntf) {
  __shared__ float lds[128 * 65];
  const int tid = threadIdx.x, eL = tid >> 1, half = tid & 1, co = half * 32;
  const int e = blockIdx.x * 128 + eL;
  const int r = edges[e], c = edges[NE + e];
  float* lrow = lds + eL * 65;

  float dx = coord[r * 3 + 0] - coord[c * 3 + 0];
  float dy = coord[r * 3 + 1] - coord[c * 3 + 1];
  float dz = coord[r * 3 + 2] - coord[c * 3 + 2];
  float nrm = sqrtf(dx * dx + dy * dy + dz * dz);
  float inv = 1.0f / (nrm + 1e-8f);
  dx *= inv; dy *= inv; dz *= inv;
  float ir = dx * dx + dy * dy + dz * dz;

  float in[36];
#pragma unroll
  for (int v = 0; v < 5; ++v) {
    float s = 0.f;
#pragma unroll
    for (int d = 0; d < 3; ++d)
      s += nv[(size_t)r * 15 + v * 3 + d] * nv[(size_t)c * 15 + v * 3 + d];
    in[v] = s;
  }
  {
    float cexp = -0.5f;
#pragma unroll
    for (int k = 0; k < 15; ++k) { in[5 + k] = __expf(ir * cexp); cexp *= (1.0f / 2.25f); }
  }
#pragma unroll
  for (int k = 0; k < 16; ++k) in[20 + k] = ea[(size_t)e * 16 + k];

  // layer 1 chunk (x in registers -> must fully unroll)
  float acc[32];
#pragma unroll
  for (int j = 0; j < 32; ++j) acc[j] = b1[co + j];
#pragma unroll
  for (int k = 0; k < 36; ++k) {
    const float x = in[k];
    const float* wr = w1 + (size_t)k * 64 + co;
#pragma unroll
    for (int j = 0; j < 32; ++j) acc[j] = fmaf(x, wr[j], acc[j]);
  }
#pragma unroll
  for (int j = 0; j < 32; ++j) lrow[co + j] = fsilu(acc[j]);
  __syncthreads();

  // layer 2 chunk
#pragma unroll
  for (int j = 0; j < 32; ++j) acc[j] = b2[co + j];
#pragma unroll 2
  for (int k = 0; k < 64; ++k) {
    const float x = lrow[k];
    const float* wr = w2 + (size_t)k * 64 + co;
#pragma unroll
    for (int j = 0; j < 32; ++j) acc[j] = fmaf(x, wr[j], acc[j]);
  }
#pragma unroll
  for (int j = 0; j < 32; ++j) acc[j] = fsilu(acc[j]);
  store32(pos + (size_t)e * 64 + co, acc);
  __syncthreads();
#pragma unroll
  for (int j = 0; j < 32; ++j) lrow[co + j] = acc[j];   // pos into LDS
  __syncthreads();

  // x head
  float a3[32];
#pragma unroll
  for (int j = 0; j < 32; ++j) a3[j] = bx1[co + j];
#pragma unroll 2
  for (int k = 0; k < 64; ++k) {
    const float x = lrow[k];
    const float* wr = wx1 + (size_t)k * 64 + co;
#pragma unroll
    for (int j = 0; j < 32; ++j) a3[j] = fmaf(x, wr[j], a3[j]);
  }
  float xp = 0.f;
#pragma unroll
  for (int j = 0; j < 32; ++j) xp = fmaf(fsilu(a3[j]), wx2[co + j], xp);
  __syncthreads();
  lrow[half] = xp;
  __syncthreads();
  if (half == 0) {
    float xs = lrow[0] + lrow[1] + bx2[0];
    float t = ue[e] * xs;
    atomicAdd(&x_sum[r * 3 + 0], dx * t);
    atomicAdd(&x_sum[r * 3 + 1], dy * t);
    atomicAdd(&x_sum[r * 3 + 2], dz * t);
    atomicAdd(&cntf[r], 1.0f);
  }
}

// ---------------- z ----------------
__global__ void LB
k_z(const float* __restrict__ chem, const float* __restrict__ pos,
    const float* __restrict__ wsh, const float* __restrict__ bsh,
    const float* __restrict__ watt, const float* __restrict__ batt,
    float* __restrict__ z) {
  __shared__ float lds[256];
  const int tid = threadIdx.x, eL = tid >> 1, half = tid & 1, co = half * 32;
  const int e = blockIdx.x * 128 + eL;
  float acc[32];
#pragma unroll
  for (int j = 0; j < 32; ++j) acc[j] = bsh[co + j];
  gemm32<64>(chem + (size_t)e * 64, wsh + co, acc);
  float z0[32];
  float ap = 0.f;
#pragma unroll
  for (int j = 0; j < 32; j += 4) {
    float4 p4 = *(const float4*)(pos + (size_t)e * 64 + co + j);
    z0[j + 0] = fsilu(acc[j + 0]) * p4.x;
    z0[j + 1] = fsilu(acc[j + 1]) * p4.y;
    z0[j + 2] = fsilu(acc[j + 2]) * p4.z;
    z0[j + 3] = fsilu(acc[j + 3]) * p4.w;
  }
#pragma unroll
  for (int j = 0; j < 32; ++j) ap = fmaf(z0[j], watt[co + j], ap);
  lds[tid] = ap;
  __syncthreads();
  float sg = fsig(batt[0] + ap + lds[tid ^ 1]);
  float* zr = z + (size_t)e * 64 + co;
#pragma unroll
  for (int j = 0; j < 32; j += 4)
    *(float4*)(zr + j) = make_float4(z0[j]*sg, z0[j+1]*sg, z0[j+2]*sg, z0[j+3]*sg);
}

// ---------------- per-head k_, v, b ----------------
__global__ void LB
k_kvb(const float* __restrict__ z, const float* __restrict__ wk,
      const float* __restrict__ wv, const float* __restrict__ wb,
      float* __restrict__ kb, float* __restrict__ vb, float* __restrict__ bb) {
  const int tid = threadIdx.x, eL = tid >> 1, half = tid & 1, co = half * 32;
  const int e = blockIdx.x * 128 + eL;
  const float* zr = z + (size_t)e * 64;
  float acc[32];
#pragma unroll
  for (int j = 0; j < 32; ++j) acc[j] = 0.f;
  gemm32<64>(zr, wk + co, acc);
  store32(kb + (size_t)e * 64 + co, acc);
#pragma unroll
  for (int j = 0; j < 32; ++j) acc[j] = 0.f;
  gemm32<64>(zr, wv + co, acc);
  store32(vb + (size_t)e * 64 + co, acc);
  if (half == 0) {
    float b = 0.f;
#pragma unroll 2
    for (int k = 0; k < 64; k += 4) {
      float4 z4 = *(const float4*)(zr + k);
      b = fmaf(z4.x, wb[k], b);   b = fmaf(z4.y, wb[k+1], b);
      b = fmaf(z4.z, wb[k+2], b); b = fmaf(z4.w, wb[k+3], b);
    }
    bb[e] = b;
  }
}

// ---------------- per-head attention, fused m accumulate ----------------
__global__ void LB
k_attn(const float* __restrict__ z, const float* __restrict__ kb,
       const float* __restrict__ vb, const float* __restrict__ bb,
       const int* __restrict__ klist,
       const float* __restrict__ wq, const float* __restrict__ wg,
       const float* __restrict__ bg,
       const float* __restrict__ wout, const float* __restrict__ bout,
       float* __restrict__ m, int first) {
  __shared__ float lds[128 * 65];
  const int tid = threadIdx.x, eL = tid >> 1, half = tid & 1, co = half * 32;
  const int e = blockIdx.x * 128 + eL;
  const float* zr = z + (size_t)e * 64;
  float* lrow = lds + eL * 65;

  // q chunk
  float q[32];
#pragma unroll
  for (int j = 0; j < 32; ++j) q[j] = 0.f;
  gemm32<64>(zr, wq + co, q);

  int i2[8], j2[8];
#pragma unroll
  for (int kn = 0; kn < 8; ++kn) {
    i2[kn] = klist[(size_t)e * 16 + kn];
    j2[kn] = klist[(size_t)e * 16 + 8 + kn];
  }
  // partial alpha over my 32 channels
#pragma unroll 1
  for (int kn = 0; kn < 8; ++kn) {
    float d = 0.f;
    if (i2[kn] >= 0) {
      const float* kr = kb + (size_t)i2[kn] * 64 + co;
#pragma unroll
      for (int kk = 0; kk < 32; kk += 4) {
        float4 k4 = *(const float4*)(kr + kk);
        d = fmaf(k4.x, q[kk+0], d); d = fmaf(k4.y, q[kk+1], d);
        d = fmaf(k4.z, q[kk+2], d); d = fmaf(k4.w, q[kk+3], d);
      }
    }
    lrow[half * 8 + kn] = d;
  }
  __syncthreads();
  float alpha[8];
#pragma unroll
  for (int kn = 0; kn < 8; ++kn) {
    if (i2[kn] < 0) alpha[kn] = -10000.0f;
    else alpha[kn] = (lrow[kn] + lrow[8 + kn]) * 0.125f + bb[j2[kn]];
  }
  float mx = alpha[0];
#pragma unroll
  for (int kn = 1; kn < 8; ++kn) mx = fmaxf(mx, alpha[kn]);
  float p[8], s = 0.f;
#pragma unroll
  for (int kn = 0; kn < 8; ++kn) { p[kn] = __expf(alpha[kn] - mx); s += p[kn]; }
  float is = 1.0f / s;
#pragma unroll
  for (int kn = 0; kn < 8; ++kn) p[kn] *= is;
  __syncthreads();   // alpha region free before mm reuse

  // out chunk = sum_k p[k] * v[i2[k]][co..co+32)
  float outc[32];
#pragma unroll
  for (int j = 0; j < 32; ++j) outc[j] = 0.f;
#pragma unroll 1
  for (int kn = 0; kn < 8; ++kn) {
    int vi = (i2[kn] < 0) ? (NE - 1) : i2[kn];   // jax v[-1] wraps
    const float* vr = vb + (size_t)vi * 64 + co;
    float pk = p[kn];
#pragma unroll
    for (int kk = 0; kk < 32; kk += 4) {
      float4 v4 = *(const float4*)(vr + kk);
      outc[kk+0] = fmaf(pk, v4.x, outc[kk+0]);
      outc[kk+1] = fmaf(pk, v4.y, outc[kk+1]);
      outc[kk+2] = fmaf(pk, v4.z, outc[kk+2]);
      outc[kk+3] = fmaf(pk, v4.w, outc[kk+3]);
    }
  }
  // gate chunk
  {
    float g[32];
#pragma unroll
    for (int j = 0; j < 32; ++j) g[j] = bg[co + j];
    gemm32<64>(zr, wg + co, g);
#pragma unroll
    for (int j = 0; j < 32; ++j) outc[j] *= fsig(g[j]);   // ho chunk
  }
  // mm partial (all 64 outputs from my 32 ho channels)
  float mm[64];
  if (half == 0) {
    if (first) {
#pragma unroll
      for (int j = 0; j < 64; ++j) mm[j] = bout[j];
    } else {
#pragma unroll
      for (int j = 0; j < 64; j += 4) {
        float4 m4 = *(const float4*)(m + (size_t)e * 64 + j);
        mm[j] = m4.x; mm[j+1] = m4.y; mm[j+2] = m4.z; mm[j+3] = m4.w;
      }
    }
  } else {
#pragma unroll
    for (int j = 0; j < 64; ++j) mm[j] = 0.f;
  }
#pragma unroll 2
  for (int k = 0; k < 32; ++k) {
    const float* wr = wout + (size_t)(co + k) * 64;
    const float x = outc[k];
#pragma unroll
    for (int j = 0; j < 64; ++j) mm[j] = fmaf(x, wr[j], mm[j]);
  }
  if (half == 1) {
#pragma unroll
    for (int j = 0; j < 64; ++j) lrow[j] = mm[j];
  }
  __syncthreads();
  if (half == 0) {
#pragma unroll
    for (int j = 0; j < 64; j += 4)
      *(float4*)(m + (size_t)e * 64 + j) =
          make_float4(mm[j] + lrow[j], mm[j+1] + lrow[j+1],
                      mm[j+2] + lrow[j+2], mm[j+3] + lrow[j+3]);
  }
}

// ---------------- scatter m into m_sum ----------------
__global__ void __launch_bounds__(256)
k_scatter(const float* __restrict__ m, const int* __restrict__ edges,
          float* __restrict__ m_sum) {
  int i = blockIdx.x * 256 + threadIdx.x;
  if (i >= NE * 64) return;
  int e = i >> 6, j = i & 63;
  atomicAdd(&m_sum[(size_t)edges[e] * 64 + j], m[i]);
}

// ---------------- final node update ----------------
__global__ void __launch_bounds__(256)
k_final(const float* __restrict__ h, const float* __restrict__ na,
        const float* __restrict__ coord, const float* __restrict__ icoord,
        const float* __restrict__ m_sum, const float* __restrict__ x_sum,
        const float* __restrict__ cntf,
        const float* __restrict__ wh1, const float* __restrict__ bh1,
        const float* __restrict__ wh2, const float* __restrict__ bh2,
        float* __restrict__ scr, float* __restrict__ out) {
  int n = blockIdx.x * 256 + threadIdx.x;
  if (n >= NN) return;
  float invc = 1.0f / fmaxf(cntf[n], 1.0f);

#pragma unroll
  for (int d = 0; d < 3; ++d)
    out[(size_t)NN * 64 + n * 3 + d] =
        0.2f * icoord[n * 3 + d] + 0.8f * coord[n * 3 + d] + x_sum[n * 3 + d] * invc;

  const float* hr = h  + (size_t)n * 64;
  const float* nr = na + (size_t)n * 64;
  const float* mr = m_sum + (size_t)n * 64;
  float* srow = scr + (size_t)n * 64;

#pragma unroll 1
  for (int cc = 0; cc < 64; cc += 32) {
    float acc[32];
#pragma unroll
    for (int j = 0; j < 32; ++j) acc[j] = bh1[cc + j];
    gemm32<64>(hr, wh1 + cc, acc);
    gemm32<64>(nr, wh1 + 64 * 64 + cc, acc);
    float macc[32];
#pragma unroll
    for (int j = 0; j < 32; ++j) macc[j] = 0.f;
    gemm32<64>(mr, wh1 + 128 * 64 + cc, macc);
#pragma unroll
    for (int j = 0; j < 32; ++j) acc[j] = fsilu(fmaf(invc, macc[j], acc[j]));
    store32(srow + cc, acc);
  }
#pragma unroll 1
  for (int cc = 0; cc < 64; cc += 32) {
    float acc[32];
#pragma unroll
    for (int j = 0; j < 32; ++j) acc[j] = bh2[cc + j];
    gemm32<64>(srow, wh2 + cc, acc);
#pragma unroll
    for (int j = 0; j < 32; j += 4) {
      float4 h4 = *(const float4*)(hr + cc + j);
      *(float4*)(out + (size_t)n * 64 + cc + j) =
          make_float4(acc[j] + h4.x, acc[j+1] + h4.y, acc[j+2] + h4.z, acc[j+3] + h4.w);
    }
  }
}

extern "C" void kernel_launch(void* const* d_in, const int* in_sizes, int n_in,
                              void* d_out, int out_size, void* d_ws, size_t ws_size,
                              hipStream_t stream) {
  (void)in_sizes; (void)n_in; (void)out_size; (void)ws_size;
  const float* h      = (const float*)d_in[0];
  const float* coord  = (const float*)d_in[1];
  const int*   edges  = (const int*)  d_in[2];
  const float* nvecs  = (const float*)d_in[3];
  const float* ea     = (const float*)d_in[4];
  const float* na     = (const float*)d_in[5];
  const float* icoord = (const float*)d_in[6];
  const int*   klist  = (const int*)  d_in[7];
  const float* w_chem1 = (const float*)d_in[8];
  const float* b_chem1 = (const float*)d_in[9];
  const float* w_chem2 = (const float*)d_in[10];
  const float* b_chem2 = (const float*)d_in[11];
  const float* w_pos1  = (const float*)d_in[12];
  const float* b_pos1  = (const float*)d_in[13];
  const float* w_pos2  = (const float*)d_in[14];
  const float* b_pos2  = (const float*)d_in[15];
  const float* w_sh    = (const float*)d_in[16];
  const float* b_sh    = (const float*)d_in[17];
  const float* w_att   = (const float*)d_in[18];
  const float* b_att   = (const float*)d_in[19];
  const float* wq      = (const float*)d_in[20];
  const float* wk      = (const float*)d_in[21];
  const float* wv      = (const float*)d_in[22];
  const float* wb      = (const float*)d_in[23];
  const float* wg      = (const float*)d_in[24];
  const float* bg      = (const float*)d_in[25];
  const float* w_out   = (const float*)d_in[26];
  const float* b_out   = (const float*)d_in[27];
  const float* wu1     = (const float*)d_in[28];
  const float* bu1     = (const float*)d_in[29];
  const float* wu2     = (const float*)d_in[30];
  const float* bu2     = (const float*)d_in[31];
  const float* wx1     = (const float*)d_in[32];
  const float* bx1     = (const float*)d_in[33];
  const float* wx2     = (const float*)d_in[34];
  const float* bx2     = (const float*)d_in[35];
  const float* wh1     = (const float*)d_in[36];
  const float* bh1     = (const float*)d_in[37];
  const float* wh2     = (const float*)d_in[38];
  const float* bh2     = (const float*)d_in[39];

  float* out = (float*)d_out;
  float* ws  = (float*)d_ws;
  float* z     = ws;                       // E x 64
  float* kb    = z    + (size_t)NE * 64;   // E x 64 (chem staging not needed now)
  float* vb    = kb   + (size_t)NE * 64;   // E x 64
  float* mbuf  = vb   + (size_t)NE * 64;   // E x 64: chem, then m accumulator
  float* ue    = mbuf + (size_t)NE * 64;   // E
  float* be    = ue   + NE;                // E
  float* m_sum = be   + NE;                // N x 64
  float* x_sum = m_sum + (size_t)NN * 64;  // N x 3
  float* cntf  = x_sum + (size_t)NN * 3;   // N
  float* nscr  = cntf + NN;                // N x 64

  hipMemsetAsync(m_sum, 0, (size_t)(NN * 64 + NN * 3 + NN) * sizeof(float), stream);

  dim3 blk(256), grid(NE / 128);   // 1250 blocks, 2 threads/edge
  k_chem<<<grid, blk, 0, stream>>>(h, na, ea, edges, w_chem1, b_chem1, w_chem2, b_chem2,
                                   wu1, bu1, wu2, bu2, mbuf, ue);
  k_pos<<<grid, blk, 0, stream>>>(coord, nvecs, ea, edges, w_pos1, b_pos1, w_pos2, b_pos2,
                                  wx1, bx1, wx2, bx2, ue, vb, x_sum, cntf);
  k_z<<<grid, blk, 0, stream>>>(mbuf, vb, w_sh, b_sh, w_att, b_att, z);
  for (int hd = 0; hd < 4; ++hd) {
    k_kvb<<<grid, blk, 0, stream>>>(z, wk + hd * 4096, wv + hd * 4096, wb + hd * 64,
                                    kb, vb, be);
    k_attn<<<grid, blk, 0, stream>>>(z, kb, vb, be, klist,
                                     wq + hd * 4096, wg + hd * 4096, bg + hd * 64,
                                     w_out + hd * 64 * 64, b_out, mbuf, hd == 0 ? 1 : 0);
  }
  k_scatter<<<dim3((NE * 64) / 256), blk, 0, stream>>>(mbuf, edges, m_sum);
  k_final<<<dim3((NN + 255) / 256), blk, 0, stream>>>(h, na, coord, icoord, m_sum, x_sum,
                                                      cntf, wh1, bh1, wh2, bh2, nscr, out);
}

// Round 4
// 1992.353 us; speedup vs baseline: 3.0656x; 3.0656x over previous
//
#include <hip/hip_runtime.h>
#include <math.h>

#define NE 160000
#define NN 10000

#define DEV __device__ __forceinline__

DEV float fsilu(float x) { return x / (1.0f + __expf(-x)); }
DEV float fsig(float x)  { return 1.0f / (1.0f + __expf(-x)); }

// 2-edge, 32-out GEMM chunk: a{0,1}[j] += x{0,1}[k] * w[k*64+j]
// w is block-uniform (co from blockIdx.y) -> s_load broadcast; each weight
// feeds 2 FMAs.
template<int K>
DEV void g2(const float* __restrict__ x0, const float* __restrict__ x1,
            const float* __restrict__ w, float (&a0)[32], float (&a1)[32]) {
#pragma unroll 4
  for (int k = 0; k < K; k += 4) {
    const float4 u = *(const float4*)(x0 + k);
    const float4 v = *(const float4*)(x1 + k);
    const float* wr = w + (size_t)k * 64;
#pragma unroll
    for (int j = 0; j < 32; ++j) { float ww = wr[j];       a0[j] = fmaf(u.x, ww, a0[j]); a1[j] = fmaf(v.x, ww, a1[j]); }
#pragma unroll
    for (int j = 0; j < 32; ++j) { float ww = wr[64 + j];  a0[j] = fmaf(u.y, ww, a0[j]); a1[j] = fmaf(v.y, ww, a1[j]); }
#pragma unroll
    for (int j = 0; j < 32; ++j) { float ww = wr[128 + j]; a0[j] = fmaf(u.z, ww, a0[j]); a1[j] = fmaf(v.z, ww, a1[j]); }
#pragma unroll
    for (int j = 0; j < 32; ++j) { float ww = wr[192 + j]; a0[j] = fmaf(u.w, ww, a0[j]); a1[j] = fmaf(v.w, ww, a1[j]); }
  }
}

// 1-edge, 32-out GEMM chunk
template<int K>
DEV void g1(const float* __restrict__ x, const float* __restrict__ w,
            float (&a)[32]) {
#pragma unroll 4
  for (int k = 0; k < K; k += 4) {
    const float4 u = *(const float4*)(x + k);
    const float* wr = w + (size_t)k * 64;
#pragma unroll
    for (int j = 0; j < 32; ++j) a[j] = fmaf(u.x, wr[j], a[j]);
#pragma unroll
    for (int j = 0; j < 32; ++j) a[j] = fmaf(u.y, wr[64 + j], a[j]);
#pragma unroll
    for (int j = 0; j < 32; ++j) a[j] = fmaf(u.z, wr[128 + j], a[j]);
#pragma unroll
    for (int j = 0; j < 32; ++j) a[j] = fmaf(u.w, wr[192 + j], a[j]);
  }
}

DEV void store32(float* dst, const float (&a)[32]) {
#pragma unroll
  for (int j = 0; j < 32; j += 4)
    *(float4*)(dst + j) = make_float4(a[j], a[j+1], a[j+2], a[j+3]);
}

// ---------- chem layer 1: 272 -> 64 silu (y-split chunks, 2 edges/thread) ----------
__global__ void __launch_bounds__(128)
k_chem1(const float* __restrict__ h, const float* __restrict__ na,
        const float* __restrict__ ea, const int* __restrict__ edges,
        const float* __restrict__ w1, const float* __restrict__ b1,
        float* __restrict__ act1c) {
  const int tid = threadIdx.x;
  const int e0 = blockIdx.x * 256 + tid, e1 = e0 + 128;
  const int co = blockIdx.y * 32;
  const int r0 = edges[e0], c0 = edges[NE + e0];
  const int r1 = edges[e1], c1 = edges[NE + e1];
  float a0[32], a1[32];
#pragma unroll
  for (int j = 0; j < 32; ++j) { a0[j] = b1[co + j]; a1[j] = a0[j]; }
  g2<64>(h  + (size_t)r0 * 64, h  + (size_t)r1 * 64, w1 + co,            a0, a1);
  g2<64>(h  + (size_t)c0 * 64, h  + (size_t)c1 * 64, w1 +  64 * 64 + co, a0, a1);
  g2<64>(na + (size_t)r0 * 64, na + (size_t)r1 * 64, w1 + 128 * 64 + co, a0, a1);
  g2<64>(na + (size_t)c0 * 64, na + (size_t)c1 * 64, w1 + 192 * 64 + co, a0, a1);
  g2<16>(ea + (size_t)e0 * 16, ea + (size_t)e1 * 16, w1 + 256 * 64 + co, a0, a1);
#pragma unroll
  for (int j = 0; j < 32; ++j) { a0[j] = fsilu(a0[j]); a1[j] = fsilu(a1[j]); }
  store32(act1c + (size_t)e0 * 64 + co, a0);
  store32(act1c + (size_t)e1 * 64 + co, a1);
}

// ---------- pos layer 1: 36 -> 64 silu (y-split, 1 edge/thread) ----------
__global__ void __launch_bounds__(256)
k_pos1(const float* __restrict__ coord, const float* __restrict__ nv,
       const float* __restrict__ ea, const int* __restrict__ edges,
       const float* __restrict__ w1, const float* __restrict__ b1,
       float* __restrict__ act1p) {
  const int e = blockIdx.x * 256 + threadIdx.x;
  const int co = blockIdx.y * 32;
  const int r = edges[e], c = edges[NE + e];

  float dx = coord[r * 3 + 0] - coord[c * 3 + 0];
  float dy = coord[r * 3 + 1] - coord[c * 3 + 1];
  float dz = coord[r * 3 + 2] - coord[c * 3 + 2];
  float nrm = sqrtf(dx * dx + dy * dy + dz * dz);
  float inv = 1.0f / (nrm + 1e-8f);
  dx *= inv; dy *= inv; dz *= inv;
  float ir = dx * dx + dy * dy + dz * dz;

  float in[36];
#pragma unroll
  for (int v = 0; v < 5; ++v) {
    float s = 0.f;
#pragma unroll
    for (int d = 0; d < 3; ++d)
      s += nv[(size_t)r * 15 + v * 3 + d] * nv[(size_t)c * 15 + v * 3 + d];
    in[v] = s;
  }
  {
    float cexp = -0.5f;
#pragma unroll
    for (int k = 0; k < 15; ++k) { in[5 + k] = __expf(ir * cexp); cexp *= (1.0f / 2.25f); }
  }
#pragma unroll
  for (int k = 0; k < 16; k += 4) {
    float4 e4 = *(const float4*)(ea + (size_t)e * 16 + k);
    in[20 + k] = e4.x; in[21 + k] = e4.y; in[22 + k] = e4.z; in[23 + k] = e4.w;
  }

  float acc[32];
#pragma unroll
  for (int j = 0; j < 32; ++j) acc[j] = b1[co + j];
#pragma unroll
  for (int k = 0; k < 36; ++k) {
    const float x = in[k];
    const float* wr = w1 + (size_t)k * 64 + co;
#pragma unroll
    for (int j = 0; j < 32; ++j) acc[j] = fmaf(x, wr[j], acc[j]);
  }
#pragma unroll
  for (int j = 0; j < 32; ++j) acc[j] = fsilu(acc[j]);
  store32(act1p + (size_t)e * 64 + co, acc);
}

// ---------- layer 2 of both MLPs: chem & pos (y-split, 2 edges/thread) ----------
__global__ void __launch_bounds__(128)
k_l2(const float* __restrict__ act1c, const float* __restrict__ act1p,
     const float* __restrict__ w2c, const float* __restrict__ b2c,
     const float* __restrict__ w2p, const float* __restrict__ b2p,
     float* __restrict__ chem, float* __restrict__ pos) {
  const int tid = threadIdx.x;
  const int e0 = blockIdx.x * 256 + tid, e1 = e0 + 128;
  const int co = blockIdx.y * 32;
  float a0[32], a1[32];
#pragma unroll
  for (int j = 0; j < 32; ++j) { a0[j] = b2c[co + j]; a1[j] = a0[j]; }
  g2<64>(act1c + (size_t)e0 * 64, act1c + (size_t)e1 * 64, w2c + co, a0, a1);
#pragma unroll
  for (int j = 0; j < 32; ++j) { a0[j] = fsilu(a0[j]); a1[j] = fsilu(a1[j]); }
  store32(chem + (size_t)e0 * 64 + co, a0);
  store32(chem + (size_t)e1 * 64 + co, a1);
#pragma unroll
  for (int j = 0; j < 32; ++j) { a0[j] = b2p[co + j]; a1[j] = a0[j]; }
  g2<64>(act1p + (size_t)e0 * 64, act1p + (size_t)e1 * 64, w2p + co, a0, a1);
#pragma unroll
  for (int j = 0; j < 32; ++j) { a0[j] = fsilu(a0[j]); a1[j] = fsilu(a1[j]); }
  store32(pos + (size_t)e0 * 64 + co, a0);
  store32(pos + (size_t)e1 * 64 + co, a1);
}

// ---------- z0 = silu(chem@Wsh+b)*pos; partial att-gate dot into ae ----------
__global__ void __launch_bounds__(128)
k_z(const float* __restrict__ chem, const float* __restrict__ pos,
    const float* __restrict__ wsh, const float* __restrict__ bsh,
    const float* __restrict__ watt,
    float* __restrict__ z, float* __restrict__ ae) {
  const int tid = threadIdx.x;
  const int e0 = blockIdx.x * 256 + tid, e1 = e0 + 128;
  const int co = blockIdx.y * 32;
  float a0[32], a1[32];
#pragma unroll
  for (int j = 0; j < 32; ++j) { a0[j] = bsh[co + j]; a1[j] = a0[j]; }
  g2<64>(chem + (size_t)e0 * 64, chem + (size_t)e1 * 64, wsh + co, a0, a1);
  float ap0 = 0.f, ap1 = 0.f;
#pragma unroll
  for (int j = 0; j < 32; j += 4) {
    float4 p0 = *(const float4*)(pos + (size_t)e0 * 64 + co + j);
    float4 p1 = *(const float4*)(pos + (size_t)e1 * 64 + co + j);
    a0[j+0] = fsilu(a0[j+0]) * p0.x; a0[j+1] = fsilu(a0[j+1]) * p0.y;
    a0[j+2] = fsilu(a0[j+2]) * p0.z; a0[j+3] = fsilu(a0[j+3]) * p0.w;
    a1[j+0] = fsilu(a1[j+0]) * p1.x; a1[j+1] = fsilu(a1[j+1]) * p1.y;
    a1[j+2] = fsilu(a1[j+2]) * p1.z; a1[j+3] = fsilu(a1[j+3]) * p1.w;
  }
#pragma unroll
  for (int j = 0; j < 32; ++j) {
    float ww = watt[co + j];
    ap0 = fmaf(a0[j], ww, ap0); ap1 = fmaf(a1[j], ww, ap1);
  }
  store32(z + (size_t)e0 * 64 + co, a0);
  store32(z + (size_t)e1 * 64 + co, a1);
  atomicAdd(&ae[e0], ap0);
  atomicAdd(&ae[e1], ap1);
}

// ---------- scalars: gate z in place, u & x heads, x_trans atomics, b[4] ----------
__global__ void __launch_bounds__(256)
k_scalars(const float* __restrict__ coord, const int* __restrict__ edges,
          const float* __restrict__ chem, const float* __restrict__ pos,
          const float* __restrict__ ae, const float* __restrict__ batt,
          const float* __restrict__ wu1, const float* __restrict__ bu1,
          const float* __restrict__ wu2, const float* __restrict__ bu2,
          const float* __restrict__ wx1, const float* __restrict__ bx1,
          const float* __restrict__ wx2, const float* __restrict__ bx2,
          const float* __restrict__ wb,
          float* __restrict__ z, float* __restrict__ be,
          float* __restrict__ x_sum, float* __restrict__ cntf) {
  const int e = blockIdx.x * 256 + threadIdx.x;
  const int r = edges[e], c = edges[NE + e];
  float* zr = z + (size_t)e * 64;
  const float sg = fsig(batt[0] + ae[e]);

  // gate z in place; keep gated row in regs for the b dots
  float zv[64];
#pragma unroll
  for (int j = 0; j < 64; j += 4) {
    float4 z4 = *(const float4*)(zr + j);
    zv[j+0] = z4.x * sg; zv[j+1] = z4.y * sg; zv[j+2] = z4.z * sg; zv[j+3] = z4.w * sg;
    *(float4*)(zr + j) = make_float4(zv[j+0], zv[j+1], zv[j+2], zv[j+3]);
  }
  // per-head b scalars
#pragma unroll
  for (int hd = 0; hd < 4; ++hd) {
    float b = 0.f;
#pragma unroll
    for (int k = 0; k < 64; ++k) b = fmaf(zv[k], wb[hd * 64 + k], b);
    be[(size_t)hd * NE + e] = b;
  }

  // u head: silu(chem@wu1+bu1)@wu2 + bu2 (two 32-chunk passes)
  const float* crow = chem + (size_t)e * 64;
  float u = bu2[0];
#pragma unroll 1
  for (int cc = 0; cc < 64; cc += 32) {
    float acc[32];
#pragma unroll
    for (int j = 0; j < 32; ++j) acc[j] = bu1[cc + j];
    g1<64>(crow, wu1 + cc, acc);
#pragma unroll
    for (int j = 0; j < 32; ++j) u = fmaf(fsilu(acc[j]), wu2[cc + j], u);
  }
  // x head
  const float* prow = pos + (size_t)e * 64;
  float xs = bx2[0];
#pragma unroll 1
  for (int cc = 0; cc < 64; cc += 32) {
    float acc[32];
#pragma unroll
    for (int j = 0; j < 32; ++j) acc[j] = bx1[cc + j];
    g1<64>(prow, wx1 + cc, acc);
#pragma unroll
    for (int j = 0; j < 32; ++j) xs = fmaf(fsilu(acc[j]), wx2[cc + j], xs);
  }

  float dx = coord[r * 3 + 0] - coord[c * 3 + 0];
  float dy = coord[r * 3 + 1] - coord[c * 3 + 1];
  float dz = coord[r * 3 + 2] - coord[c * 3 + 2];
  float nrm = sqrtf(dx * dx + dy * dy + dz * dz);
  float inv = 1.0f / (nrm + 1e-8f);
  float t = u * xs;
  atomicAdd(&x_sum[r * 3 + 0], dx * inv * t);
  atomicAdd(&x_sum[r * 3 + 1], dy * inv * t);
  atomicAdd(&x_sum[r * 3 + 2], dz * inv * t);
  atomicAdd(&cntf[r], 1.0f);
}

// ---------- per-head k_, v (y-split, 2 edges/thread) ----------
__global__ void __launch_bounds__(128)
k_kvb(const float* __restrict__ z, const float* __restrict__ wk,
      const float* __restrict__ wv,
      float* __restrict__ kb, float* __restrict__ vb) {
  const int tid = threadIdx.x;
  const int e0 = blockIdx.x * 256 + tid, e1 = e0 + 128;
  const int co = blockIdx.y * 32;
  const float* z0 = z + (size_t)e0 * 64;
  const float* z1 = z + (size_t)e1 * 64;
  float a0[32], a1[32];
#pragma unroll
  for (int j = 0; j < 32; ++j) { a0[j] = 0.f; a1[j] = 0.f; }
  g2<64>(z0, z1, wk + co, a0, a1);
  store32(kb + (size_t)e0 * 64 + co, a0);
  store32(kb + (size_t)e1 * 64 + co, a1);
#pragma unroll
  for (int j = 0; j < 32; ++j) { a0[j] = 0.f; a1[j] = 0.f; }
  g2<64>(z0, z1, wv + co, a0, a1);
  store32(vb + (size_t)e0 * 64 + co, a0);
  store32(vb + (size_t)e1 * 64 + co, a1);
}

// ---------- per-head attention + fused outproj accumulate ----------
__global__ void __launch_bounds__(256)
k_attn(const float* __restrict__ z, const float* __restrict__ kb,
       const float* __restrict__ vb, const float* __restrict__ bb,
       const int* __restrict__ klist,
       const float* __restrict__ wq, const float* __restrict__ wg,
       const float* __restrict__ bg,
       const float* __restrict__ wout, const float* __restrict__ bout,
       float* __restrict__ m, int first) {
  const int e = blockIdx.x * 256 + threadIdx.x;
  const float* zr = z + (size_t)e * 64;

  // q = z @ wq (full 64 via two chunk passes)
  float qa[32], qb2[32];
#pragma unroll
  for (int j = 0; j < 32; ++j) qa[j] = 0.f;
  g1<64>(zr, wq, qa);
#pragma unroll
  for (int j = 0; j < 32; ++j) qb2[j] = 0.f;
  g1<64>(zr, wq + 32, qb2);

  int i2[8], j2[8];
#pragma unroll
  for (int kn = 0; kn < 8; ++kn) {
    i2[kn] = klist[(size_t)e * 16 + kn];
    j2[kn] = klist[(size_t)e * 16 + 8 + kn];
  }
  float alpha[8];
#pragma unroll 1
  for (int kn = 0; kn < 8; ++kn) {
    if (i2[kn] < 0) { alpha[kn] = -10000.0f; continue; }
    const float* kr = kb + (size_t)i2[kn] * 64;
    float d0 = 0.f, d1 = 0.f, d2 = 0.f, d3 = 0.f;
#pragma unroll
    for (int kk = 0; kk < 32; kk += 4) {
      float4 k4 = *(const float4*)(kr + kk);
      d0 = fmaf(k4.x, qa[kk+0], d0); d1 = fmaf(k4.y, qa[kk+1], d1);
      d2 = fmaf(k4.z, qa[kk+2], d2); d3 = fmaf(k4.w, qa[kk+3], d3);
    }
#pragma unroll
    for (int kk = 0; kk < 32; kk += 4) {
      float4 k4 = *(const float4*)(kr + 32 + kk);
      d0 = fmaf(k4.x, qb2[kk+0], d0); d1 = fmaf(k4.y, qb2[kk+1], d1);
      d2 = fmaf(k4.z, qb2[kk+2], d2); d3 = fmaf(k4.w, qb2[kk+3], d3);
    }
    alpha[kn] = (d0 + d1 + d2 + d3) * 0.125f + bb[j2[kn]];
  }
  float mx = alpha[0];
#pragma unroll
  for (int kn = 1; kn < 8; ++kn) mx = fmaxf(mx, alpha[kn]);
  float p[8], s = 0.f;
#pragma unroll
  for (int kn = 0; kn < 8; ++kn) { p[kn] = __expf(alpha[kn] - mx); s += p[kn]; }
  float is = 1.0f / s;
#pragma unroll
  for (int kn = 0; kn < 8; ++kn) p[kn] *= is;

  // av: two 32-chunks (reuse qa/qb2 registers as output)
  float ova[32], ovb[32];
#pragma unroll
  for (int j = 0; j < 32; ++j) { ova[j] = 0.f; ovb[j] = 0.f; }
#pragma unroll 1
  for (int kn = 0; kn < 8; ++kn) {
    int vi = (i2[kn] < 0) ? (NE - 1) : i2[kn];   // jax v[-1] wraps
    const float* vr = vb + (size_t)vi * 64;
    float pk = p[kn];
#pragma unroll
    for (int kk = 0; kk < 32; kk += 4) {
      float4 v4 = *(const float4*)(vr + kk);
      ova[kk+0] = fmaf(pk, v4.x, ova[kk+0]); ova[kk+1] = fmaf(pk, v4.y, ova[kk+1]);
      ova[kk+2] = fmaf(pk, v4.z, ova[kk+2]); ova[kk+3] = fmaf(pk, v4.w, ova[kk+3]);
    }
#pragma unroll
    for (int kk = 0; kk < 32; kk += 4) {
      float4 v4 = *(const float4*)(vr + 32 + kk);
      ovb[kk+0] = fmaf(pk, v4.x, ovb[kk+0]); ovb[kk+1] = fmaf(pk, v4.y, ovb[kk+1]);
      ovb[kk+2] = fmaf(pk, v4.z, ovb[kk+2]); ovb[kk+3] = fmaf(pk, v4.w, ovb[kk+3]);
    }
  }
  // gate: ho = sigmoid(z@wg+bg) * av, per chunk
  {
    float g[32];
#pragma unroll
    for (int j = 0; j < 32; ++j) g[j] = bg[j];
    g1<64>(zr, wg, g);
#pragma unroll
    for (int j = 0; j < 32; ++j) ova[j] *= fsig(g[j]);
#pragma unroll
    for (int j = 0; j < 32; ++j) g[j] = bg[32 + j];
    g1<64>(zr, wg + 32, g);
#pragma unroll
    for (int j = 0; j < 32; ++j) ovb[j] *= fsig(g[j]);
  }
  // mm = (first ? bout : m_row) + ho @ wout
  float mm[64];
  if (first) {
#pragma unroll
    for (int j = 0; j < 64; ++j) mm[j] = bout[j];
  } else {
#pragma unroll
    for (int j = 0; j < 64; j += 4) {
      float4 m4 = *(const float4*)(m + (size_t)e * 64 + j);
      mm[j] = m4.x; mm[j+1] = m4.y; mm[j+2] = m4.z; mm[j+3] = m4.w;
    }
  }
#pragma unroll 2
  for (int k = 0; k < 32; ++k) {
    const float* wr = wout + (size_t)k * 64;
    const float x = ova[k];
#pragma unroll
    for (int j = 0; j < 64; ++j) mm[j] = fmaf(x, wr[j], mm[j]);
  }
#pragma unroll 2
  for (int k = 0; k < 32; ++k) {
    const float* wr = wout + (size_t)(32 + k) * 64;
    const float x = ovb[k];
#pragma unroll
    for (int j = 0; j < 64; ++j) mm[j] = fmaf(x, wr[j], mm[j]);
  }
#pragma unroll
  for (int j = 0; j < 64; j += 4)
    *(float4*)(m + (size_t)e * 64 + j) = make_float4(mm[j], mm[j+1], mm[j+2], mm[j+3]);
}

// ---------- scatter m into m_sum ----------
__global__ void __launch_bounds__(256)
k_scatter(const float* __restrict__ m, const int* __restrict__ edges,
          float* __restrict__ m_sum) {
  int i = blockIdx.x * 256 + threadIdx.x;
  if (i >= NE * 64) return;
  int e = i >> 6, j = i & 63;
  atomicAdd(&m_sum[(size_t)edges[e] * 64 + j], m[i]);
}

// ---------- final node update ----------
__global__ void __launch_bounds__(256)
k_final(const float* __restrict__ h, const float* __restrict__ na,
        const float* __restrict__ coord, const float* __restrict__ icoord,
        const float* __restrict__ m_sum, const float* __restrict__ x_sum,
        const float* __restrict__ cntf,
        const float* __restrict__ wh1, const float* __restrict__ bh1,
        const float* __restrict__ wh2, const float* __restrict__ bh2,
        float* __restrict__ scr, float* __restrict__ out) {
  int n = blockIdx.x * 256 + threadIdx.x;
  if (n >= NN) return;
  float invc = 1.0f / fmaxf(cntf[n], 1.0f);

#pragma unroll
  for (int d = 0; d < 3; ++d)
    out[(size_t)NN * 64 + n * 3 + d] =
        0.2f * icoord[n * 3 + d] + 0.8f * coord[n * 3 + d] + x_sum[n * 3 + d] * invc;

  const float* hr = h  + (size_t)n * 64;
  const float* nr = na + (size_t)n * 64;
  const float* mr = m_sum + (size_t)n * 64;
  float* srow = scr + (size_t)n * 64;

#pragma unroll 1
  for (int cc = 0; cc < 64; cc += 32) {
    float acc[32];
#pragma unroll
    for (int j = 0; j < 32; ++j) acc[j] = bh1[cc + j];
    g1<64>(hr, wh1 + cc, acc);
    g1<64>(nr, wh1 + 64 * 64 + cc, acc);
    float macc[32];
#pragma unroll
    for (int j = 0; j < 32; ++j) macc[j] = 0.f;
    g1<64>(mr, wh1 + 128 * 64 + cc, macc);
#pragma unroll
    for (int j = 0; j < 32; ++j) acc[j] = fsilu(fmaf(invc, macc[j], acc[j]));
    store32(srow + cc, acc);
  }
#pragma unroll 1
  for (int cc = 0; cc < 64; cc += 32) {
    float acc[32];
#pragma unroll
    for (int j = 0; j < 32; ++j) acc[j] = bh2[cc + j];
    g1<64>(srow, wh2 + cc, acc);
#pragma unroll
    for (int j = 0; j < 32; j += 4) {
      float4 h4 = *(const float4*)(hr + cc + j);
      *(float4*)(out + (size_t)n * 64 + cc + j) =
          make_float4(acc[j] + h4.x, acc[j+1] + h4.y, acc[j+2] + h4.z, acc[j+3] + h4.w);
    }
  }
}

extern "C" void kernel_launch(void* const* d_in, const int* in_sizes, int n_in,
                              void* d_out, int out_size, void* d_ws, size_t ws_size,
                              hipStream_t stream) {
  (void)in_sizes; (void)n_in; (void)out_size; (void)ws_size;
  const float* h      = (const float*)d_in[0];
  const float* coord  = (const float*)d_in[1];
  const int*   edges  = (const int*)  d_in[2];
  const float* nvecs  = (const float*)d_in[3];
  const float* ea     = (const float*)d_in[4];
  const float* na     = (const float*)d_in[5];
  const float* icoord = (const float*)d_in[6];
  const int*   klist  = (const int*)  d_in[7];
  const float* w_chem1 = (const float*)d_in[8];
  const float* b_chem1 = (const float*)d_in[9];
  const float* w_chem2 = (const float*)d_in[10];
  const float* b_chem2 = (const float*)d_in[11];
  const float* w_pos1  = (const float*)d_in[12];
  const float* b_pos1  = (const float*)d_in[13];
  const float* w_pos2  = (const float*)d_in[14];
  const float* b_pos2  = (const float*)d_in[15];
  const float* w_sh    = (const float*)d_in[16];
  const float* b_sh    = (const float*)d_in[17];
  const float* w_att   = (const float*)d_in[18];
  const float* b_att   = (const float*)d_in[19];
  const float* wq      = (const float*)d_in[20];
  const float* wk      = (const float*)d_in[21];
  const float* wv      = (const float*)d_in[22];
  const float* wb      = (const float*)d_in[23];
  const float* wg      = (const float*)d_in[24];
  const float* bg      = (const float*)d_in[25];
  const float* w_out   = (const float*)d_in[26];
  const float* b_out   = (const float*)d_in[27];
  const float* wu1     = (const float*)d_in[28];
  const float* bu1     = (const float*)d_in[29];
  const float* wu2     = (const float*)d_in[30];
  const float* bu2     = (const float*)d_in[31];
  const float* wx1     = (const float*)d_in[32];
  const float* bx1     = (const float*)d_in[33];
  const float* wx2     = (const float*)d_in[34];
  const float* bx2     = (const float*)d_in[35];
  const float* wh1     = (const float*)d_in[36];
  const float* bh1     = (const float*)d_in[37];
  const float* wh2     = (const float*)d_in[38];
  const float* bh2     = (const float*)d_in[39];

  float* out = (float*)d_out;
  float* ws  = (float*)d_ws;
  // 4 big E*64 regions, phase-reused:
  //   R1: act1c -> z      R2: act1p -> kb
  //   R3: chem  -> vb     R4: pos   -> mbuf
  float* R1 = ws;
  float* R2 = R1 + (size_t)NE * 64;
  float* R3 = R2 + (size_t)NE * 64;
  float* R4 = R3 + (size_t)NE * 64;
  float* ae    = R4 + (size_t)NE * 64;       // E (zeroed)
  float* m_sum = ae + NE;                    // NN*64 (zeroed)
  float* x_sum = m_sum + (size_t)NN * 64;    // NN*3 (zeroed)
  float* cntf  = x_sum + (size_t)NN * 3;     // NN (zeroed)
  float* be    = cntf + NN;                  // 4*E
  float* nscr  = be + (size_t)4 * NE;        // NN*64

  hipMemsetAsync(ae, 0, (size_t)(NE + NN * 64 + NN * 3 + NN) * sizeof(float), stream);

  dim3 b128(128), b256(256);
  dim3 gsplit2(NE / 256, 2);   // 625 x 2 blocks of 128 (2 edges/thread)
  dim3 gsplit1(NE / 256, 2);   // 625 x 2 blocks of 256 (1 edge/thread)
  dim3 gflat(NE / 256);        // 625 blocks of 256

  k_chem1<<<gsplit2, b128, 0, stream>>>(h, na, ea, edges, w_chem1, b_chem1, R1);
  k_pos1 <<<gsplit1, b256, 0, stream>>>(coord, nvecs, ea, edges, w_pos1, b_pos1, R2);
  k_l2   <<<gsplit2, b128, 0, stream>>>(R1, R2, w_chem2, b_chem2, w_pos2, b_pos2, R3, R4);
  k_z    <<<gsplit2, b128, 0, stream>>>(R3, R4, w_sh, b_sh, w_att, R1, ae);
  k_scalars<<<gflat, b256, 0, stream>>>(coord, edges, R3, R4, ae, b_att,
                                        wu1, bu1, wu2, bu2, wx1, bx1, wx2, bx2, wb,
                                        R1, be, x_sum, cntf);
  for (int hd = 0; hd < 4; ++hd) {
    k_kvb<<<gsplit2, b128, 0, stream>>>(R1, wk + hd * 4096, wv + hd * 4096, R2, R3);
    k_attn<<<gflat, b256, 0, stream>>>(R1, R2, R3, be + (size_t)hd * NE, klist,
                                       wq + hd * 4096, wg + hd * 4096, bg + hd * 64,
                                       w_out + hd * 64 * 64, b_out, R4, hd == 0 ? 1 : 0);
  }
  k_scatter<<<dim3((NE * 64) / 256), b256, 0, stream>>>(R4, edges, m_sum);
  k_final<<<dim3((NN + 255) / 256), b256, 0, stream>>>(h, na, coord, icoord, m_sum, x_sum,
                                                       cntf, wh1, bh1, wh2, bh2, nscr, out);
}